// Round 16
// baseline (237.965 us; speedup 1.0000x reference)
//
#include <hip/hip_runtime.h>
#include <hip/hip_bf16.h>

// Multi-head attention (B=2, S=2048, D_MODEL=1024, H=16, DK=64), causal.
// Outputs: out [B,S,DM] fp32  ++  attn_weights [B,H,S,S] fp32 (concatenated).

#define DM 1024
#define NH 16
#define DKH 64
#define BB 2
#define SS 2048
#define MM (BB*SS)   // 4096 rows

typedef __bf16 bf16_t;
typedef __bf16 bf16x4 __attribute__((ext_vector_type(4)));
typedef __bf16 bf16x8 __attribute__((ext_vector_type(8)));
typedef float  f32x4  __attribute__((ext_vector_type(4)));

#define EXP2F(x) __builtin_amdgcn_exp2f(x)

__device__ __forceinline__ f32x4 mfma16(bf16x8 a, bf16x8 b, f32x4 c) {
    return __builtin_amdgcn_mfma_f32_16x16x32_bf16(a, b, c, 0, 0, 0);
}
__device__ __forceinline__ bf16x8 cat8(bf16x4 lo, bf16x4 hi) {
    bf16x8 r;
    r[0]=lo[0]; r[1]=lo[1]; r[2]=lo[2]; r[3]=lo[3];
    r[4]=hi[0]; r[5]=hi[1]; r[6]=hi[2]; r[7]=hi[3];
    return r;
}

// async global->LDS, 16B per lane (wave-uniform LDS base + lane*16)
__device__ __forceinline__ void gload16(const bf16_t* g, bf16_t* l) {
    __builtin_amdgcn_global_load_lds(
        (const __attribute__((address_space(1))) void*)g,
        (__attribute__((address_space(3))) void*)l, 16, 0, 0);
}

// 16B chunk read from LINEAR [R][64] LDS tile staged with source-side XOR
// swizzle (LDS chunk s of row r holds global chunk s^(r&7)).
__device__ __forceinline__ bf16x8 ldsw(const bf16_t* t, int row, int ch) {
    return *(const bf16x8*)(t + row * 64 + (((ch ^ row) & 7) << 3));
}

// ---------------------------------------------------------------------------
// fp32 -> bf16 convert, all 7 tensors in ONE dispatch. grid (2048, 4):
// y<3 -> inputs q/k/v (2048 blocks each); y==3 -> 4 weights (512 blocks each).
// ---------------------------------------------------------------------------
__global__ __launch_bounds__(256)
void cvt_all(const float* __restrict__ q, const float* __restrict__ k,
             const float* __restrict__ v, const float* __restrict__ wq,
             const float* __restrict__ wk, const float* __restrict__ wv,
             const float* __restrict__ wo,
             bf16_t* __restrict__ qb, bf16_t* __restrict__ kb,
             bf16_t* __restrict__ vb, bf16_t* __restrict__ wqb,
             bf16_t* __restrict__ wkb, bf16_t* __restrict__ wvb,
             bf16_t* __restrict__ wob)
{
    const int y = blockIdx.y;
    const float* s;
    bf16_t* d;
    size_t i;
    if (y < 3) {
        s = (y == 0) ? q : (y == 1) ? k : v;
        d = (y == 0) ? qb : (y == 1) ? kb : vb;
        i = (size_t)(blockIdx.x * 256 + threadIdx.x) * 8;
    } else {
        const int t = blockIdx.x >> 9;           // 0..3
        s = (t == 0) ? wq : (t == 1) ? wk : (t == 2) ? wv : wo;
        d = (t == 0) ? wqb : (t == 1) ? wkb : (t == 2) ? wvb : wob;
        i = (size_t)((blockIdx.x & 511) * 256 + threadIdx.x) * 8;
    }
    float4 f0 = *(const float4*)(s + i);
    float4 f1 = *(const float4*)(s + i + 4);
    bf16x8 o;
    o[0]=(bf16_t)f0.x; o[1]=(bf16_t)f0.y; o[2]=(bf16_t)f0.z; o[3]=(bf16_t)f0.w;
    o[4]=(bf16_t)f1.x; o[5]=(bf16_t)f1.y; o[6]=(bf16_t)f1.z; o[7]=(bf16_t)f1.w;
    *(bf16x8*)(d + i) = o;
}

// ---------------------------------------------------------------------------
// Shared GEMM core: 128x64 tile, BK=64, SINGLE-buffered m97-style 2-barrier
// K-loop (24 KB LDS -> high co-residency; cross-block overlap covers the
// vmcnt drain, per m114). XCD-bijective bm mapping.
// Epilogue mode: 0 = Qp (frag-perm, x0.125*log2e), 1 = Kp (frag-perm),
// 2 = Vt (transposed [dk][key], key-perm), 3 = fp32 flat.
// ---------------------------------------------------------------------------
__device__ __forceinline__
void gemm_core(const bf16_t* __restrict__ A, const bf16_t* __restrict__ W,
               const float* __restrict__ bias, void* __restrict__ out,
               int bid, int mode)
{
    __shared__ bf16_t As[128 * 64];
    __shared__ bf16_t Bs[64 * 64];

    const int tid  = threadIdx.x;
    const int lane = tid & 63;
    const int wid  = tid >> 6;
    const int wm = wid >> 1, wn = wid & 1;        // 2x2 waves: 64 rows x 32 cols
    const int xcd  = bid & 7, slot = bid >> 3;
    const int bm   = xcd * 4 + (slot >> 4);       // [0,32)
    const int bn   = slot & 15;                   // [0,16)
    const int c = lane & 15, g = lane >> 4;
    const int sr = tid >> 3, sch = tid & 7;       // staging row(0..31), chunk
    const int scol = ((sch ^ (sr & 7)) << 3);     // pre-swizzled source col

    f32x4 acc[4][2] = {};

    const bf16_t* Ab = A + (size_t)(bm * 128 + sr) * DM + scol;
    const bf16_t* Wb = W + (size_t)(bn * 64 + sr) * DM + scol;

    for (int kt = 0; kt < DM / 64; ++kt) {
        {   // stage tile kt (async -> LDS), single buffer
            bf16_t* asl = &As[wid * 512];
            bf16_t* bsl = &Bs[wid * 512];
            #pragma unroll
            for (int j = 0; j < 4; ++j)
                gload16(Ab + (size_t)(j * 32) * DM + kt * 64, asl + j * 2048);
            #pragma unroll
            for (int j = 0; j < 2; ++j)
                gload16(Wb + (size_t)(j * 32) * DM + kt * 64, bsl + j * 2048);
        }
        __syncthreads();                          // staged tile kt landed
        #pragma unroll
        for (int kh = 0; kh < 2; ++kh) {
            bf16x8 am[4], bw[2];
            #pragma unroll
            for (int f = 0; f < 4; ++f)
                am[f] = ldsw(As, wm * 64 + f * 16 + c, kh * 4 + g);
            #pragma unroll
            for (int f = 0; f < 2; ++f)
                bw[f] = ldsw(Bs, wn * 32 + f * 16 + c, kh * 4 + g);
            #pragma unroll
            for (int fm = 0; fm < 4; ++fm)
                #pragma unroll
                for (int fn = 0; fn < 2; ++fn)
                    acc[fm][fn] = mfma16(am[fm], bw[fn], acc[fm][fn]);
        }
        __syncthreads();                          // reads done before restage
    }

    // D[row][col]: col = lane&15 (c), row = 4*g + reg
    #pragma unroll
    for (int fm = 0; fm < 4; ++fm) {
        #pragma unroll
        for (int fn = 0; fn < 2; ++fn) {
            const int col = bn * 64 + wn * 32 + fn * 16 + c;
            const float bcol = bias[col];
            if (mode == 2) {
                const int h = (col >> 6) & 15, dk = col & 63;
                const int row0 = bm * 128 + wm * 64 + fm * 16 + 4 * g;
                const int b = row0 >> 11, s0 = row0 & (SS - 1);
                bf16x4 pv;
                #pragma unroll
                for (int r = 0; r < 4; ++r) pv[r] = (bf16_t)(acc[fm][fn][r] + bcol);
                size_t idx = ((size_t)((b * NH + h) * DKH + dk)) * SS
                           + ((s0 >> 5) << 5) + g * 8 + (fm & 1) * 4;
                *(bf16x4*)&((bf16_t*)out)[idx] = pv;
            } else {
                #pragma unroll
                for (int r = 0; r < 4; ++r) {
                    const int row = bm * 128 + wm * 64 + fm * 16 + 4 * g + r;
                    float val = acc[fm][fn][r] + bcol;
                    if (mode == 3) {
                        __builtin_nontemporal_store(
                            val, &((float*)out)[(size_t)row * DM + col]);
                    } else {
                        if (mode == 0)
                            val *= 0.125f * 1.44269504f;   // scale * log2(e)
                        const int b = row >> 11, s = row & (SS - 1);
                        const int h = (col >> 6) & 15;
                        const int fnl = (col >> 4) & 3;
                        // frag perm: pos = (fn>>1)*32 + (c>>2)*8 + (fn&1)*4 + (c&3)
                        const int pos = ((fnl >> 1) << 5) + ((c >> 2) << 3)
                                      + ((fnl & 1) << 2) + (c & 3);
                        ((bf16_t*)out)[((size_t)(b * NH + h) * SS + s) * DKH + pos]
                            = (bf16_t)val;
                    }
                }
            }
        }
    }
}

// Fused Q/K/V projection GEMMs: grid 1536, proj = blockIdx.x >> 9.
__global__ __launch_bounds__(256)
void mha_gemm_qkv(const bf16_t* __restrict__ qb, const bf16_t* __restrict__ kb,
                  const bf16_t* __restrict__ vb,
                  const bf16_t* __restrict__ wqb, const bf16_t* __restrict__ wkb,
                  const bf16_t* __restrict__ wvb,
                  const float* __restrict__ b_q, const float* __restrict__ b_k,
                  const float* __restrict__ b_v,
                  bf16_t* __restrict__ Qp, bf16_t* __restrict__ Kp,
                  bf16_t* __restrict__ Vt)
{
    const int proj = blockIdx.x >> 9;            // 0,1,2 (block-uniform)
    const int bid  = blockIdx.x & 511;
    const bf16_t* A = (proj == 0) ? qb : (proj == 1) ? kb : vb;
    const bf16_t* W = (proj == 0) ? wqb : (proj == 1) ? wkb : wvb;
    const float* bi = (proj == 0) ? b_q : (proj == 1) ? b_k : b_v;
    void* out       = (proj == 0) ? (void*)Qp : (proj == 1) ? (void*)Kp : (void*)Vt;
    gemm_core(A, W, bi, out, bid, proj);
}

// Output projection GEMM (fp32 out), grid 512.
__global__ __launch_bounds__(256)
void mha_gemm_o(const bf16_t* __restrict__ aout, const bf16_t* __restrict__ wob,
                const float* __restrict__ b_o, float* __restrict__ out)
{
    gemm_core(aout, wob, b_o, out, blockIdx.x, 3);
}

// ---------------------------------------------------------------------------
// Attention v14 = v13 with MAKESPAN-BALANCED 1-D grid: block bid and
// bid+256 (which co-reside on the same CU under round-robin dispatch) get
// complementary staging loads: staged(bid)+staged(bid+256) = 49 tiles for
// every CU. Decode: hi=bid>>8, j7=bid&7, bh=(bid&255)>>3,
// jb = hi ? 15-j7 : j7. Schedule/staging/guards identical to v13.
// ---------------------------------------------------------------------------
__global__ __launch_bounds__(256)
void mha_attn14(const bf16_t* __restrict__ Qp, const bf16_t* __restrict__ Kp,
                const bf16_t* __restrict__ Vt, float* __restrict__ attn,
                bf16_t* __restrict__ aout)
{
    __shared__ bf16_t SB[32768];                 // 64 KB pool

    const int tid = threadIdx.x, lane = tid & 63, w = tid >> 6;
    const int c = lane & 15, g = lane >> 4;
    const int bid = blockIdx.x;
    const int hi = bid >> 8, lo = bid & 255;
    const int j7 = lo & 7;
    const int jb = hi ? (15 - j7) : j7;          // complementary pairing
    const int bh = lo >> 3;                      // [0,32)
    const int b = bh >> 4, h = bh & 15;

    const int qtA = jb, qtB = 31 - jb;           // light / heavy q-tiles
    const int q0A = qtA * 64, q0B = qtB * 64;
    const int q0wA = q0A + w * 16, q0wB = q0B + w * 16;
    const int ntA = qtA + 1, ntB = qtB + 1;      // tiles per half

    const bf16_t* Qb = Qp + (size_t)bh * SS * DKH;
    const bf16_t* Kb = Kp + (size_t)bh * SS * DKH;
    const bf16_t* Vb = Vt + (size_t)bh * DKH * SS;
    float* attb = attn + (size_t)bh * SS * SS;

    // staging map: 256 threads x 16B = 32 rows of a [*][64] tile per call
    const int sr = tid >> 3, sch = tid & 7;      // rows 0..31, chunk 0..7
    const int ssw = ((sch ^ (sr & 7)) << 3);     // swizzled source col (elems)

    // Q fragments for both halves (permuted layout)
    const bf16_t* qrA = Qb + (size_t)(q0wA + c) * DKH;
    const bf16x8 qaA0 = *(const bf16x8*)(qrA + g * 8);
    const bf16x8 qaA1 = *(const bf16x8*)(qrA + 32 + g * 8);
    const bf16_t* qrB = Qb + (size_t)(q0wB + c) * DKH;
    const bf16x8 qaB0 = *(const bf16x8*)(qrB + g * 8);
    const bf16x8 qaB1 = *(const bf16x8*)(qrB + 32 + g * 8);

    // ============ pass 1: row sums, 256-key rounds (K only) ============
#define STAGE_K4(dst, rr) do {                                              \
        const bf16_t* s0_ = Kb + (size_t)(4 * (rr)) * 4096 + sr * 64 + ssw; \
        bf16_t* d_ = (dst);                                                 \
        gload16(s0_,         d_ + w * 512);                                 \
        gload16(s0_ + 2048,  d_ + 2048 + w * 512);                          \
        gload16(s0_ + 4096,  d_ + 4096 + w * 512);                          \
        gload16(s0_ + 6144,  d_ + 6144 + w * 512);                          \
        gload16(s0_ + 8192,  d_ + 8192 + w * 512);                          \
        gload16(s0_ + 10240, d_ + 10240 + w * 512);                         \
        gload16(s0_ + 12288, d_ + 12288 + w * 512);                         \
        gload16(s0_ + 14336, d_ + 14336 + w * 512);                         \
    } while (0)

    const int nr4 = (ntB + 3) >> 2;              // 256-key rounds
    STAGE_K4(SB, 0);
    float lsumA = 0.f, lsumB = 0.f;
    for (int rr = 0; rr < nr4; ++rr) {
        const int cur = rr & 1;
        __syncthreads();                         // round rr staged
        if (rr + 1 < nr4) STAGE_K4((cur ^ 1) ? SB + 16384 : SB, rr + 1);
        const bf16_t* kbase = cur ? SB + 16384 : SB;
        #pragma unroll
        for (int t = 0; t < 4; ++t) {
            const int kt = 4 * rr + t;
            if (kt < ntB) {                      // block-uniform
                const bf16_t* ks = kbase + t * 4096;
                // half B (heavy)
                {
                    f32x4 s[4] = {};
                    #pragma unroll
                    for (int sb = 0; sb < 4; ++sb) {
                        bf16x8 k0 = ldsw(ks, sb * 16 + c, g);
                        bf16x8 k1 = ldsw(ks, sb * 16 + c, 4 | g);
                        s[sb] = mfma16(k0, qaB0, s[sb]);
                        s[sb] = mfma16(k1, qaB1, s[sb]);
                    }
                    if (kt == qtB) {
                        #pragma unroll
                        for (int sb = 0; sb < 4; ++sb)
                            #pragma unroll
                            for (int r = 0; r < 4; ++r)
                                if (sb * 16 + 4 * g + r <= w * 16 + c)
                                    lsumB += EXP2F(s[sb][r]);
                    } else {
                        #pragma unroll
                        for (int sb = 0; sb < 4; ++sb)
                            #pragma unroll
                            for (int r = 0; r < 4; ++r)
                                lsumB += EXP2F(s[sb][r]);
                    }
                }
                // half A (light), block-uniform guard
                if (kt < ntA) {
                    f32x4 s[4] = {};
                    #pragma unroll
                    for (int sb = 0; sb < 4; ++sb) {
                        bf16x8 k0 = ldsw(ks, sb * 16 + c, g);
                        bf16x8 k1 = ldsw(ks, sb * 16 + c, 4 | g);
                        s[sb] = mfma16(k0, qaA0, s[sb]);
                        s[sb] = mfma16(k1, qaA1, s[sb]);
                    }
                    if (kt == qtA) {
                        #pragma unroll
                        for (int sb = 0; sb < 4; ++sb)
                            #pragma unroll
                            for (int r = 0; r < 4; ++r)
                                if (sb * 16 + 4 * g + r <= w * 16 + c)
                                    lsumA += EXP2F(s[sb][r]);
                    } else {
                        #pragma unroll
                        for (int sb = 0; sb < 4; ++sb)
                            #pragma unroll
                            for (int r = 0; r < 4; ++r)
                                lsumA += EXP2F(s[sb][r]);
                    }
                }
            }
        }
    }
#undef STAGE_K4
    lsumA += __shfl_xor(lsumA, 16);
    lsumA += __shfl_xor(lsumA, 32);
    lsumB += __shfl_xor(lsumB, 16);
    lsumB += __shfl_xor(lsumB, 32);
    const float invlA = 1.f / lsumA;
    const float invlB = 1.f / lsumB;

    // ============ pass 2: P write + PV, 128-key rounds (K + V) ============
#define STAGE_K2(dst, rr) do {                                              \
        const bf16_t* s0_ = Kb + (size_t)(2 * (rr)) * 4096 + sr * 64 + ssw; \
        bf16_t* d_ = (dst);                                                 \
        gload16(s0_,        d_ + w * 512);                                  \
        gload16(s0_ + 2048, d_ + 2048 + w * 512);                           \
        gload16(s0_ + 4096, d_ + 4096 + w * 512);                           \
        gload16(s0_ + 6144, d_ + 6144 + w * 512);                           \
    } while (0)

#define STAGE_V2(dst, rr) do {                                              \
        const bf16_t* v0_ = Vb + (size_t)sr * SS + (2 * (rr)) * 64 + ssw;   \
        bf16_t* d_ = (dst);                                                 \
        gload16(v0_,                        d_ + w * 512);                  \
        gload16(v0_ + (size_t)32 * SS,      d_ + 2048 + w * 512);           \
        gload16(v0_ + 64,                   d_ + 4096 + w * 512);           \
        gload16(v0_ + (size_t)32 * SS + 64, d_ + 6144 + w * 512);           \
    } while (0)

    const int nr2 = (ntB + 1) >> 1;              // 128-key rounds
    __syncthreads();                             // pass-1 LDS reads done
    STAGE_K2(SB, 0);
    STAGE_V2(SB + 16384, 0);
    f32x4 oA[4] = {}, oB[4] = {};
    for (int rr = 0; rr < nr2; ++rr) {
        const int cur = rr & 1;
        __syncthreads();
        if (rr + 1 < nr2) {
            STAGE_K2((cur ^ 1) ? SB + 8192 : SB, rr + 1);
            STAGE_V2((cur ^ 1) ? SB + 24576 : SB + 16384, rr + 1);
        }
        const bf16_t* kbase = cur ? SB + 8192 : SB;
        const bf16_t* vbase = cur ? SB + 24576 : SB + 16384;
        #pragma unroll
        for (int t = 0; t < 2; ++t) {
            const int kt = 2 * rr + t;
            if (kt < ntB) {
                const bf16_t* ks = kbase + t * 4096;
                const bf16_t* vs = vbase + t * 4096;
                // half B (heavy)
                {
                    f32x4 s[4] = {};
                    #pragma unroll
                    for (int sb = 0; sb < 4; ++sb) {
                        bf16x8 k0 = ldsw(ks, sb * 16 + c, g);
                        bf16x8 k1 = ldsw(ks, sb * 16 + c, 4 | g);
                        s[sb] = mfma16(k0, qaB0, s[sb]);
                        s[sb] = mfma16(k1, qaB1, s[sb]);
                    }
                    const bool diag = (kt == qtB);
                    bf16x4 pb[4];
                    float* prow = attb + (size_t)(q0wB + c) * SS + kt * 64 + 4 * g;
                    #pragma unroll
                    for (int sb = 0; sb < 4; ++sb) {
                        f32x4 pf;
                        #pragma unroll
                        for (int r = 0; r < 4; ++r) {
                            bool msk = diag && (sb * 16 + 4 * g + r > w * 16 + c);
                            float p = msk ? 0.f : EXP2F(s[sb][r]) * invlB;
                            pf[r] = p;
                            pb[sb][r] = (bf16_t)p;
                        }
                        *(f32x4*)(prow + sb * 16) = pf;
                    }
                    const bf16x8 pa0 = cat8(pb[0], pb[1]);
                    const bf16x8 pa1 = cat8(pb[2], pb[3]);
                    #pragma unroll
                    for (int fn = 0; fn < 4; ++fn) {
                        bf16x8 v0 = ldsw(vs, fn * 16 + c, g);
                        bf16x8 v1 = ldsw(vs, fn * 16 + c, 4 | g);
                        oB[fn] = mfma16(pa0, v0, oB[fn]);
                        oB[fn] = mfma16(pa1, v1, oB[fn]);
                    }
                }
                // half A (light), block-uniform guard
                if (kt < ntA) {
                    f32x4 s[4] = {};
                    #pragma unroll
                    for (int sb = 0; sb < 4; ++sb) {
                        bf16x8 k0 = ldsw(ks, sb * 16 + c, g);
                        bf16x8 k1 = ldsw(ks, sb * 16 + c, 4 | g);
                        s[sb] = mfma16(k0, qaA0, s[sb]);
                        s[sb] = mfma16(k1, qaA1, s[sb]);
                    }
                    const bool diag = (kt == qtA);
                    bf16x4 pb[4];
                    float* prow = attb + (size_t)(q0wA + c) * SS + kt * 64 + 4 * g;
                    #pragma unroll
                    for (int sb = 0; sb < 4; ++sb) {
                        f32x4 pf;
                        #pragma unroll
                        for (int r = 0; r < 4; ++r) {
                            bool msk = diag && (sb * 16 + 4 * g + r > w * 16 + c);
                            float p = msk ? 0.f : EXP2F(s[sb][r]) * invlA;
                            pf[r] = p;
                            pb[sb][r] = (bf16_t)p;
                        }
                        *(f32x4*)(prow + sb * 16) = pf;
                    }
                    const bf16x8 pa0 = cat8(pb[0], pb[1]);
                    const bf16x8 pa1 = cat8(pb[2], pb[3]);
                    #pragma unroll
                    for (int fn = 0; fn < 4; ++fn) {
                        bf16x8 v0 = ldsw(vs, fn * 16 + c, g);
                        bf16x8 v1 = ldsw(vs, fn * 16 + c, 4 | g);
                        oA[fn] = mfma16(pa0, v0, oA[fn]);
                        oA[fn] = mfma16(pa1, v1, oA[fn]);
                    }
                }
            }
        }
    }
#undef STAGE_K2
#undef STAGE_V2

    // epilogue: O -> aout (bf16, [M][DM] head-interleaved), both halves
    #pragma unroll
    for (int fn = 0; fn < 4; ++fn)
        #pragma unroll
        for (int r = 0; r < 4; ++r) {
            aout[(size_t)(b * SS + q0wB + 4 * g + r) * DM + h * DKH + fn * 16 + c]
                = (bf16_t)oB[fn][r];
            aout[(size_t)(b * SS + q0wA + 4 * g + r) * DM + h * DKH + fn * 16 + c]
                = (bf16_t)oA[fn][r];
        }

    // zero-fill masked regions (constant combined size: 31 col-tiles)
    {
        f32x4 z = {0.f, 0.f, 0.f, 0.f};
        {
            const int zr = q0A + (tid >> 2);
            float* dst = attb + (size_t)zr * SS;
            for (int col = ntA * 64 + (tid & 3) * 4; col < SS; col += 16)
                *(f32x4*)(dst + col) = z;
        }
        {
            const int zr = q0B + (tid >> 2);
            float* dst = attb + (size_t)zr * SS;
            for (int col = ntB * 64 + (tid & 3) * 4; col < SS; col += 16)
                *(f32x4*)(dst + col) = z;
        }
    }
}

// ---------------------------------------------------------------------------
extern "C" void kernel_launch(void* const* d_in, const int* in_sizes, int n_in,
                              void* d_out, int out_size, void* d_ws, size_t ws_size,
                              hipStream_t stream)
{
    const float* q   = (const float*)d_in[0];
    const float* k   = (const float*)d_in[1];
    const float* v   = (const float*)d_in[2];
    // d_in[3] = causal mask, known analytically -> unused
    const float* w_q = (const float*)d_in[4];
    const float* b_q = (const float*)d_in[5];
    const float* w_k = (const float*)d_in[6];
    const float* b_k = (const float*)d_in[7];
    const float* w_v = (const float*)d_in[8];
    const float* b_v = (const float*)d_in[9];
    const float* w_o = (const float*)d_in[10];
    const float* b_o = (const float*)d_in[11];

    float* out   = (float*)d_out;
    float* attnw = out + (size_t)MM * DM;

    bf16_t* Qp   = (bf16_t*)d_ws;                 // [B,H,S,DK-perm] bf16
    bf16_t* Kp   = Qp + (size_t)MM * DM;
    bf16_t* Vt   = Kp + (size_t)MM * DM;          // [B,H,DK,S-perm] bf16
    bf16_t* aout = Vt + (size_t)MM * DM;          // [M, DM] bf16
    bf16_t* qb   = aout + (size_t)MM * DM;        // bf16 copies of inputs
    bf16_t* kb   = qb + (size_t)MM * DM;
    bf16_t* vb   = kb + (size_t)MM * DM;
    bf16_t* wqb  = vb + (size_t)MM * DM;          // bf16 weights [DM][DM]
    bf16_t* wkb  = wqb + (size_t)DM * DM;
    bf16_t* wvb  = wkb + (size_t)DM * DM;
    bf16_t* wob  = wvb + (size_t)DM * DM;

    cvt_all<<<dim3(2048, 4), 256, 0, stream>>>(q, k, v, w_q, w_k, w_v, w_o,
                                               qb, kb, vb, wqb, wkb, wvb, wob);

    mha_gemm_qkv<<<1536, 256, 0, stream>>>(qb, kb, vb, wqb, wkb, wvb,
                                           b_q, b_k, b_v, Qp, Kp, Vt);

    mha_attn14<<<512, 256, 0, stream>>>(Qp, Kp, Vt, attnw, aout);

    mha_gemm_o<<<512, 256, 0, stream>>>(aout, wob, b_o, out);
}

// Round 17
// 226.951 us; speedup vs baseline: 1.0485x; 1.0485x over previous
//
#include <hip/hip_runtime.h>
#include <hip/hip_bf16.h>

// Multi-head attention (B=2, S=2048, D_MODEL=1024, H=16, DK=64), causal.
// Outputs: out [B,S,DM] fp32  ++  attn_weights [B,H,S,S] fp32 (concatenated).

#define DM 1024
#define NH 16
#define DKH 64
#define BB 2
#define SS 2048
#define MM (BB*SS)   // 4096 rows

typedef __bf16 bf16_t;
typedef __bf16 bf16x4 __attribute__((ext_vector_type(4)));
typedef __bf16 bf16x8 __attribute__((ext_vector_type(8)));
typedef float  f32x4  __attribute__((ext_vector_type(4)));

#define EXP2F(x) __builtin_amdgcn_exp2f(x)

__device__ __forceinline__ f32x4 mfma16(bf16x8 a, bf16x8 b, f32x4 c) {
    return __builtin_amdgcn_mfma_f32_16x16x32_bf16(a, b, c, 0, 0, 0);
}
__device__ __forceinline__ bf16x8 cat8(bf16x4 lo, bf16x4 hi) {
    bf16x8 r;
    r[0]=lo[0]; r[1]=lo[1]; r[2]=lo[2]; r[3]=lo[3];
    r[4]=hi[0]; r[5]=hi[1]; r[6]=hi[2]; r[7]=hi[3];
    return r;
}

// async global->LDS, 16B per lane (wave-uniform LDS base + lane*16)
__device__ __forceinline__ void gload16(const bf16_t* g, bf16_t* l) {
    __builtin_amdgcn_global_load_lds(
        (const __attribute__((address_space(1))) void*)g,
        (__attribute__((address_space(3))) void*)l, 16, 0, 0);
}

// 16B chunk read from LINEAR [R][64] LDS tile staged with source-side XOR
// swizzle (LDS chunk s of row r holds global chunk s^(r&7)).
__device__ __forceinline__ bf16x8 ldsw(const bf16_t* t, int row, int ch) {
    return *(const bf16x8*)(t + row * 64 + (((ch ^ row) & 7) << 3));
}

// ---------------------------------------------------------------------------
// fp32 -> bf16 convert, all 7 tensors in ONE dispatch. grid (2048, 4):
// y<3 -> inputs q/k/v (2048 blocks each); y==3 -> 4 weights (512 blocks each).
// ---------------------------------------------------------------------------
__global__ __launch_bounds__(256)
void cvt_all(const float* __restrict__ q, const float* __restrict__ k,
             const float* __restrict__ v, const float* __restrict__ wq,
             const float* __restrict__ wk, const float* __restrict__ wv,
             const float* __restrict__ wo,
             bf16_t* __restrict__ qb, bf16_t* __restrict__ kb,
             bf16_t* __restrict__ vb, bf16_t* __restrict__ wqb,
             bf16_t* __restrict__ wkb, bf16_t* __restrict__ wvb,
             bf16_t* __restrict__ wob)
{
    const int y = blockIdx.y;
    const float* s;
    bf16_t* d;
    size_t i;
    if (y < 3) {
        s = (y == 0) ? q : (y == 1) ? k : v;
        d = (y == 0) ? qb : (y == 1) ? kb : vb;
        i = (size_t)(blockIdx.x * 256 + threadIdx.x) * 8;
    } else {
        const int t = blockIdx.x >> 9;           // 0..3
        s = (t == 0) ? wq : (t == 1) ? wk : (t == 2) ? wv : wo;
        d = (t == 0) ? wqb : (t == 1) ? wkb : (t == 2) ? wvb : wob;
        i = (size_t)((blockIdx.x & 511) * 256 + threadIdx.x) * 8;
    }
    float4 f0 = *(const float4*)(s + i);
    float4 f1 = *(const float4*)(s + i + 4);
    bf16x8 o;
    o[0]=(bf16_t)f0.x; o[1]=(bf16_t)f0.y; o[2]=(bf16_t)f0.z; o[3]=(bf16_t)f0.w;
    o[4]=(bf16_t)f1.x; o[5]=(bf16_t)f1.y; o[6]=(bf16_t)f1.z; o[7]=(bf16_t)f1.w;
    *(bf16x8*)(d + i) = o;
}

// ---------------------------------------------------------------------------
// Shared GEMM core: 128x64 tile, BK=64, SINGLE-buffered m97-style 2-barrier
// K-loop (24 KB LDS -> high co-residency; cross-block overlap covers the
// vmcnt drain, per m114). XCD-bijective bm mapping.
// Epilogue mode: 0 = Qp (frag-perm, x0.125*log2e), 1 = Kp (frag-perm),
// 2 = Vt (transposed [dk][key], key-perm), 3 = fp32 flat.
// ---------------------------------------------------------------------------
__device__ __forceinline__
void gemm_core(const bf16_t* __restrict__ A, const bf16_t* __restrict__ W,
               const float* __restrict__ bias, void* __restrict__ out,
               int bid, int mode)
{
    __shared__ bf16_t As[128 * 64];
    __shared__ bf16_t Bs[64 * 64];

    const int tid  = threadIdx.x;
    const int lane = tid & 63;
    const int wid  = tid >> 6;
    const int wm = wid >> 1, wn = wid & 1;        // 2x2 waves: 64 rows x 32 cols
    const int xcd  = bid & 7, slot = bid >> 3;
    const int bm   = xcd * 4 + (slot >> 4);       // [0,32)
    const int bn   = slot & 15;                   // [0,16)
    const int c = lane & 15, g = lane >> 4;
    const int sr = tid >> 3, sch = tid & 7;       // staging row(0..31), chunk
    const int scol = ((sch ^ (sr & 7)) << 3);     // pre-swizzled source col

    f32x4 acc[4][2] = {};

    const bf16_t* Ab = A + (size_t)(bm * 128 + sr) * DM + scol;
    const bf16_t* Wb = W + (size_t)(bn * 64 + sr) * DM + scol;

    for (int kt = 0; kt < DM / 64; ++kt) {
        {   // stage tile kt (async -> LDS), single buffer
            bf16_t* asl = &As[wid * 512];
            bf16_t* bsl = &Bs[wid * 512];
            #pragma unroll
            for (int j = 0; j < 4; ++j)
                gload16(Ab + (size_t)(j * 32) * DM + kt * 64, asl + j * 2048);
            #pragma unroll
            for (int j = 0; j < 2; ++j)
                gload16(Wb + (size_t)(j * 32) * DM + kt * 64, bsl + j * 2048);
        }
        __syncthreads();                          // staged tile kt landed
        #pragma unroll
        for (int kh = 0; kh < 2; ++kh) {
            bf16x8 am[4], bw[2];
            #pragma unroll
            for (int f = 0; f < 4; ++f)
                am[f] = ldsw(As, wm * 64 + f * 16 + c, kh * 4 + g);
            #pragma unroll
            for (int f = 0; f < 2; ++f)
                bw[f] = ldsw(Bs, wn * 32 + f * 16 + c, kh * 4 + g);
            #pragma unroll
            for (int fm = 0; fm < 4; ++fm)
                #pragma unroll
                for (int fn = 0; fn < 2; ++fn)
                    acc[fm][fn] = mfma16(am[fm], bw[fn], acc[fm][fn]);
        }
        __syncthreads();                          // reads done before restage
    }

    // D[row][col]: col = lane&15 (c), row = 4*g + reg
    #pragma unroll
    for (int fm = 0; fm < 4; ++fm) {
        #pragma unroll
        for (int fn = 0; fn < 2; ++fn) {
            const int col = bn * 64 + wn * 32 + fn * 16 + c;
            const float bcol = bias[col];
            if (mode == 2) {
                const int h = (col >> 6) & 15, dk = col & 63;
                const int row0 = bm * 128 + wm * 64 + fm * 16 + 4 * g;
                const int b = row0 >> 11, s0 = row0 & (SS - 1);
                bf16x4 pv;
                #pragma unroll
                for (int r = 0; r < 4; ++r) pv[r] = (bf16_t)(acc[fm][fn][r] + bcol);
                size_t idx = ((size_t)((b * NH + h) * DKH + dk)) * SS
                           + ((s0 >> 5) << 5) + g * 8 + (fm & 1) * 4;
                *(bf16x4*)&((bf16_t*)out)[idx] = pv;
            } else {
                #pragma unroll
                for (int r = 0; r < 4; ++r) {
                    const int row = bm * 128 + wm * 64 + fm * 16 + 4 * g + r;
                    float val = acc[fm][fn][r] + bcol;
                    if (mode == 3) {
                        __builtin_nontemporal_store(
                            val, &((float*)out)[(size_t)row * DM + col]);
                    } else {
                        if (mode == 0)
                            val *= 0.125f * 1.44269504f;   // scale * log2(e)
                        const int b = row >> 11, s = row & (SS - 1);
                        const int h = (col >> 6) & 15;
                        const int fnl = (col >> 4) & 3;
                        // frag perm: pos = (fn>>1)*32 + (c>>2)*8 + (fn&1)*4 + (c&3)
                        const int pos = ((fnl >> 1) << 5) + ((c >> 2) << 3)
                                      + ((fnl & 1) << 2) + (c & 3);
                        ((bf16_t*)out)[((size_t)(b * NH + h) * SS + s) * DKH + pos]
                            = (bf16_t)val;
                    }
                }
            }
        }
    }
}

// Fused Q/K/V projection GEMMs: grid 1536, proj = blockIdx.x >> 9.
__global__ __launch_bounds__(256)
void mha_gemm_qkv(const bf16_t* __restrict__ qb, const bf16_t* __restrict__ kb,
                  const bf16_t* __restrict__ vb,
                  const bf16_t* __restrict__ wqb, const bf16_t* __restrict__ wkb,
                  const bf16_t* __restrict__ wvb,
                  const float* __restrict__ b_q, const float* __restrict__ b_k,
                  const float* __restrict__ b_v,
                  bf16_t* __restrict__ Qp, bf16_t* __restrict__ Kp,
                  bf16_t* __restrict__ Vt)
{
    const int proj = blockIdx.x >> 9;            // 0,1,2 (block-uniform)
    const int bid  = blockIdx.x & 511;
    const bf16_t* A = (proj == 0) ? qb : (proj == 1) ? kb : vb;
    const bf16_t* W = (proj == 0) ? wqb : (proj == 1) ? wkb : wvb;
    const float* bi = (proj == 0) ? b_q : (proj == 1) ? b_k : b_v;
    void* out       = (proj == 0) ? (void*)Qp : (proj == 1) ? (void*)Kp : (void*)Vt;
    gemm_core(A, W, bi, out, bid, proj);
}

// Output projection GEMM (fp32 out), grid 512.
__global__ __launch_bounds__(256)
void mha_gemm_o(const bf16_t* __restrict__ aout, const bf16_t* __restrict__ wob,
                const float* __restrict__ b_o, float* __restrict__ out)
{
    gemm_core(aout, wob, b_o, out, blockIdx.x, 3);
}

// ---------------------------------------------------------------------------
// Attention v13 (the 227.7 us anchor): fused q-tile pair {jb, 31-jb}, one
// K-sweep; pass-1 256-key rounds (K-only over the 64 KB pool), pass-2
// 128-key K+V rounds. Unconditional staging, block-uniform guards.
// Swapped QK^T, fixed-max exp2 softmax (Qp pre-scaled 0.125*log2e),
// plain-store P from registers. 2-D grid (16, 32).
// ---------------------------------------------------------------------------
__global__ __launch_bounds__(256)
void mha_attn13(const bf16_t* __restrict__ Qp, const bf16_t* __restrict__ Kp,
                const bf16_t* __restrict__ Vt, float* __restrict__ attn,
                bf16_t* __restrict__ aout)
{
    __shared__ bf16_t SB[32768];                 // 64 KB pool

    const int tid = threadIdx.x, lane = tid & 63, w = tid >> 6;
    const int c = lane & 15, g = lane >> 4;
    const int jb = blockIdx.x, bh = blockIdx.y;
    const int b = bh >> 4, h = bh & 15;

    const int qtA = jb, qtB = 31 - jb;           // light / heavy q-tiles
    const int q0A = qtA * 64, q0B = qtB * 64;
    const int q0wA = q0A + w * 16, q0wB = q0B + w * 16;
    const int ntA = qtA + 1, ntB = qtB + 1;      // tiles per half

    const bf16_t* Qb = Qp + (size_t)bh * SS * DKH;
    const bf16_t* Kb = Kp + (size_t)bh * SS * DKH;
    const bf16_t* Vb = Vt + (size_t)bh * DKH * SS;
    float* attb = attn + (size_t)bh * SS * SS;

    // staging map: 256 threads x 16B = 32 rows of a [*][64] tile per call
    const int sr = tid >> 3, sch = tid & 7;      // rows 0..31, chunk 0..7
    const int ssw = ((sch ^ (sr & 7)) << 3);     // swizzled source col (elems)

    // Q fragments for both halves (permuted layout)
    const bf16_t* qrA = Qb + (size_t)(q0wA + c) * DKH;
    const bf16x8 qaA0 = *(const bf16x8*)(qrA + g * 8);
    const bf16x8 qaA1 = *(const bf16x8*)(qrA + 32 + g * 8);
    const bf16_t* qrB = Qb + (size_t)(q0wB + c) * DKH;
    const bf16x8 qaB0 = *(const bf16x8*)(qrB + g * 8);
    const bf16x8 qaB1 = *(const bf16x8*)(qrB + 32 + g * 8);

    // ============ pass 1: row sums, 256-key rounds (K only) ============
#define STAGE_K4(dst, rr) do {                                              \
        const bf16_t* s0_ = Kb + (size_t)(4 * (rr)) * 4096 + sr * 64 + ssw; \
        bf16_t* d_ = (dst);                                                 \
        gload16(s0_,         d_ + w * 512);                                 \
        gload16(s0_ + 2048,  d_ + 2048 + w * 512);                          \
        gload16(s0_ + 4096,  d_ + 4096 + w * 512);                          \
        gload16(s0_ + 6144,  d_ + 6144 + w * 512);                          \
        gload16(s0_ + 8192,  d_ + 8192 + w * 512);                          \
        gload16(s0_ + 10240, d_ + 10240 + w * 512);                         \
        gload16(s0_ + 12288, d_ + 12288 + w * 512);                         \
        gload16(s0_ + 14336, d_ + 14336 + w * 512);                         \
    } while (0)

    const int nr4 = (ntB + 3) >> 2;              // 256-key rounds
    STAGE_K4(SB, 0);
    float lsumA = 0.f, lsumB = 0.f;
    for (int rr = 0; rr < nr4; ++rr) {
        const int cur = rr & 1;
        __syncthreads();                         // round rr staged
        if (rr + 1 < nr4) STAGE_K4((cur ^ 1) ? SB + 16384 : SB, rr + 1);
        const bf16_t* kbase = cur ? SB + 16384 : SB;
        #pragma unroll
        for (int t = 0; t < 4; ++t) {
            const int kt = 4 * rr + t;
            if (kt < ntB) {                      // block-uniform
                const bf16_t* ks = kbase + t * 4096;
                // half B (heavy)
                {
                    f32x4 s[4] = {};
                    #pragma unroll
                    for (int sb = 0; sb < 4; ++sb) {
                        bf16x8 k0 = ldsw(ks, sb * 16 + c, g);
                        bf16x8 k1 = ldsw(ks, sb * 16 + c, 4 | g);
                        s[sb] = mfma16(k0, qaB0, s[sb]);
                        s[sb] = mfma16(k1, qaB1, s[sb]);
                    }
                    if (kt == qtB) {
                        #pragma unroll
                        for (int sb = 0; sb < 4; ++sb)
                            #pragma unroll
                            for (int r = 0; r < 4; ++r)
                                if (sb * 16 + 4 * g + r <= w * 16 + c)
                                    lsumB += EXP2F(s[sb][r]);
                    } else {
                        #pragma unroll
                        for (int sb = 0; sb < 4; ++sb)
                            #pragma unroll
                            for (int r = 0; r < 4; ++r)
                                lsumB += EXP2F(s[sb][r]);
                    }
                }
                // half A (light), block-uniform guard
                if (kt < ntA) {
                    f32x4 s[4] = {};
                    #pragma unroll
                    for (int sb = 0; sb < 4; ++sb) {
                        bf16x8 k0 = ldsw(ks, sb * 16 + c, g);
                        bf16x8 k1 = ldsw(ks, sb * 16 + c, 4 | g);
                        s[sb] = mfma16(k0, qaA0, s[sb]);
                        s[sb] = mfma16(k1, qaA1, s[sb]);
                    }
                    if (kt == qtA) {
                        #pragma unroll
                        for (int sb = 0; sb < 4; ++sb)
                            #pragma unroll
                            for (int r = 0; r < 4; ++r)
                                if (sb * 16 + 4 * g + r <= w * 16 + c)
                                    lsumA += EXP2F(s[sb][r]);
                    } else {
                        #pragma unroll
                        for (int sb = 0; sb < 4; ++sb)
                            #pragma unroll
                            for (int r = 0; r < 4; ++r)
                                lsumA += EXP2F(s[sb][r]);
                    }
                }
            }
        }
    }
#undef STAGE_K4
    lsumA += __shfl_xor(lsumA, 16);
    lsumA += __shfl_xor(lsumA, 32);
    lsumB += __shfl_xor(lsumB, 16);
    lsumB += __shfl_xor(lsumB, 32);
    const float invlA = 1.f / lsumA;
    const float invlB = 1.f / lsumB;

    // ============ pass 2: P write + PV, 128-key rounds (K + V) ============
#define STAGE_K2(dst, rr) do {                                              \
        const bf16_t* s0_ = Kb + (size_t)(2 * (rr)) * 4096 + sr * 64 + ssw; \
        bf16_t* d_ = (dst);                                                 \
        gload16(s0_,        d_ + w * 512);                                  \
        gload16(s0_ + 2048, d_ + 2048 + w * 512);                           \
        gload16(s0_ + 4096, d_ + 4096 + w * 512);                           \
        gload16(s0_ + 6144, d_ + 6144 + w * 512);                           \
    } while (0)

#define STAGE_V2(dst, rr) do {                                              \
        const bf16_t* v0_ = Vb + (size_t)sr * SS + (2 * (rr)) * 64 + ssw;   \
        bf16_t* d_ = (dst);                                                 \
        gload16(v0_,                        d_ + w * 512);                  \
        gload16(v0_ + (size_t)32 * SS,      d_ + 2048 + w * 512);           \
        gload16(v0_ + 64,                   d_ + 4096 + w * 512);           \
        gload16(v0_ + (size_t)32 * SS + 64, d_ + 6144 + w * 512);           \
    } while (0)

    const int nr2 = (ntB + 1) >> 1;              // 128-key rounds
    __syncthreads();                             // pass-1 LDS reads done
    STAGE_K2(SB, 0);
    STAGE_V2(SB + 16384, 0);
    f32x4 oA[4] = {}, oB[4] = {};
    for (int rr = 0; rr < nr2; ++rr) {
        const int cur = rr & 1;
        __syncthreads();
        if (rr + 1 < nr2) {
            STAGE_K2((cur ^ 1) ? SB + 8192 : SB, rr + 1);
            STAGE_V2((cur ^ 1) ? SB + 24576 : SB + 16384, rr + 1);
        }
        const bf16_t* kbase = cur ? SB + 8192 : SB;
        const bf16_t* vbase = cur ? SB + 24576 : SB + 16384;
        #pragma unroll
        for (int t = 0; t < 2; ++t) {
            const int kt = 2 * rr + t;
            if (kt < ntB) {
                const bf16_t* ks = kbase + t * 4096;
                const bf16_t* vs = vbase + t * 4096;
                // half B (heavy)
                {
                    f32x4 s[4] = {};
                    #pragma unroll
                    for (int sb = 0; sb < 4; ++sb) {
                        bf16x8 k0 = ldsw(ks, sb * 16 + c, g);
                        bf16x8 k1 = ldsw(ks, sb * 16 + c, 4 | g);
                        s[sb] = mfma16(k0, qaB0, s[sb]);
                        s[sb] = mfma16(k1, qaB1, s[sb]);
                    }
                    const bool diag = (kt == qtB);
                    bf16x4 pb[4];
                    float* prow = attb + (size_t)(q0wB + c) * SS + kt * 64 + 4 * g;
                    #pragma unroll
                    for (int sb = 0; sb < 4; ++sb) {
                        f32x4 pf;
                        #pragma unroll
                        for (int r = 0; r < 4; ++r) {
                            bool msk = diag && (sb * 16 + 4 * g + r > w * 16 + c);
                            float p = msk ? 0.f : EXP2F(s[sb][r]) * invlB;
                            pf[r] = p;
                            pb[sb][r] = (bf16_t)p;
                        }
                        *(f32x4*)(prow + sb * 16) = pf;
                    }
                    const bf16x8 pa0 = cat8(pb[0], pb[1]);
                    const bf16x8 pa1 = cat8(pb[2], pb[3]);
                    #pragma unroll
                    for (int fn = 0; fn < 4; ++fn) {
                        bf16x8 v0 = ldsw(vs, fn * 16 + c, g);
                        bf16x8 v1 = ldsw(vs, fn * 16 + c, 4 | g);
                        oB[fn] = mfma16(pa0, v0, oB[fn]);
                        oB[fn] = mfma16(pa1, v1, oB[fn]);
                    }
                }
                // half A (light), block-uniform guard
                if (kt < ntA) {
                    f32x4 s[4] = {};
                    #pragma unroll
                    for (int sb = 0; sb < 4; ++sb) {
                        bf16x8 k0 = ldsw(ks, sb * 16 + c, g);
                        bf16x8 k1 = ldsw(ks, sb * 16 + c, 4 | g);
                        s[sb] = mfma16(k0, qaA0, s[sb]);
                        s[sb] = mfma16(k1, qaA1, s[sb]);
                    }
                    const bool diag = (kt == qtA);
                    bf16x4 pb[4];
                    float* prow = attb + (size_t)(q0wA + c) * SS + kt * 64 + 4 * g;
                    #pragma unroll
                    for (int sb = 0; sb < 4; ++sb) {
                        f32x4 pf;
                        #pragma unroll
                        for (int r = 0; r < 4; ++r) {
                            bool msk = diag && (sb * 16 + 4 * g + r > w * 16 + c);
                            float p = msk ? 0.f : EXP2F(s[sb][r]) * invlA;
                            pf[r] = p;
                            pb[sb][r] = (bf16_t)p;
                        }
                        *(f32x4*)(prow + sb * 16) = pf;
                    }
                    const bf16x8 pa0 = cat8(pb[0], pb[1]);
                    const bf16x8 pa1 = cat8(pb[2], pb[3]);
                    #pragma unroll
                    for (int fn = 0; fn < 4; ++fn) {
                        bf16x8 v0 = ldsw(vs, fn * 16 + c, g);
                        bf16x8 v1 = ldsw(vs, fn * 16 + c, 4 | g);
                        oA[fn] = mfma16(pa0, v0, oA[fn]);
                        oA[fn] = mfma16(pa1, v1, oA[fn]);
                    }
                }
            }
        }
    }
#undef STAGE_K2
#undef STAGE_V2

    // epilogue: O -> aout (bf16, [M][DM] head-interleaved), both halves
    #pragma unroll
    for (int fn = 0; fn < 4; ++fn)
        #pragma unroll
        for (int r = 0; r < 4; ++r) {
            aout[(size_t)(b * SS + q0wB + 4 * g + r) * DM + h * DKH + fn * 16 + c]
                = (bf16_t)oB[fn][r];
            aout[(size_t)(b * SS + q0wA + 4 * g + r) * DM + h * DKH + fn * 16 + c]
                = (bf16_t)oA[fn][r];
        }

    // zero-fill masked regions (constant combined size: 31 col-tiles)
    {
        f32x4 z = {0.f, 0.f, 0.f, 0.f};
        {
            const int zr = q0A + (tid >> 2);
            float* dst = attb + (size_t)zr * SS;
            for (int col = ntA * 64 + (tid & 3) * 4; col < SS; col += 16)
                *(f32x4*)(dst + col) = z;
        }
        {
            const int zr = q0B + (tid >> 2);
            float* dst = attb + (size_t)zr * SS;
            for (int col = ntB * 64 + (tid & 3) * 4; col < SS; col += 16)
                *(f32x4*)(dst + col) = z;
        }
    }
}

// ---------------------------------------------------------------------------
extern "C" void kernel_launch(void* const* d_in, const int* in_sizes, int n_in,
                              void* d_out, int out_size, void* d_ws, size_t ws_size,
                              hipStream_t stream)
{
    const float* q   = (const float*)d_in[0];
    const float* k   = (const float*)d_in[1];
    const float* v   = (const float*)d_in[2];
    // d_in[3] = causal mask, known analytically -> unused
    const float* w_q = (const float*)d_in[4];
    const float* b_q = (const float*)d_in[5];
    const float* w_k = (const float*)d_in[6];
    const float* b_k = (const float*)d_in[7];
    const float* w_v = (const float*)d_in[8];
    const float* b_v = (const float*)d_in[9];
    const float* w_o = (const float*)d_in[10];
    const float* b_o = (const float*)d_in[11];

    float* out   = (float*)d_out;
    float* attnw = out + (size_t)MM * DM;

    bf16_t* Qp   = (bf16_t*)d_ws;                 // [B,H,S,DK-perm] bf16
    bf16_t* Kp   = Qp + (size_t)MM * DM;
    bf16_t* Vt   = Kp + (size_t)MM * DM;          // [B,H,DK,S-perm] bf16
    bf16_t* aout = Vt + (size_t)MM * DM;          // [M, DM] bf16
    bf16_t* qb   = aout + (size_t)MM * DM;        // bf16 copies of inputs
    bf16_t* kb   = qb + (size_t)MM * DM;
    bf16_t* vb   = kb + (size_t)MM * DM;
    bf16_t* wqb  = vb + (size_t)MM * DM;          // bf16 weights [DM][DM]
    bf16_t* wkb  = wqb + (size_t)DM * DM;
    bf16_t* wvb  = wkb + (size_t)DM * DM;
    bf16_t* wob  = wvb + (size_t)DM * DM;

    cvt_all<<<dim3(2048, 4), 256, 0, stream>>>(q, k, v, w_q, w_k, w_v, w_o,
                                               qb, kb, vb, wqb, wkb, wvb, wob);

    mha_gemm_qkv<<<1536, 256, 0, stream>>>(qb, kb, vb, wqb, wkb, wvb,
                                           b_q, b_k, b_v, Qp, Kp, Vt);

    mha_attn13<<<dim3(16, BB * NH), 256, 0, stream>>>(Qp, Kp, Vt, attnw, aout);

    mha_gemm_o<<<512, 256, 0, stream>>>(aout, wob, b_o, out);
}